// Round 1
// baseline (375.001 us; speedup 1.0000x reference)
//
#include <hip/hip_runtime.h>
#include <hip/hip_bf16.h>

#define NT 4096   // tokens
#define DM 1024   // d_model
#define DH 4096   // d_hidden
#define NE 8      // experts

#define BM 128
#define BN 128
#define BK 32
#define BKP 40    // padded LDS K-stride (elements): 80 B, 16B-aligned

typedef short bf16x8 __attribute__((ext_vector_type(8)));
typedef float f32x4 __attribute__((ext_vector_type(4)));

static __device__ __forceinline__ unsigned short f2bf(float f) {
  union { __hip_bfloat16 h; unsigned short u; } cv;
  cv.h = __float2bfloat16(f);
  return cv.u;
}

// ---------------------------------------------------------------------------
// Gate: one wave per token. Computes 8 expert logits (double accum -> argmax
// first-max like np.argmax), scatters token into its expert's bucket, and
// converts the x row to bf16 (xb) since we're reading it anyway.
// ---------------------------------------------------------------------------
__global__ __launch_bounds__(256) void gate_route_kernel(
    const float* __restrict__ x, const float* __restrict__ gw,
    const float* __restrict__ gb, int* __restrict__ counts,
    int* __restrict__ bucket, __hip_bfloat16* __restrict__ xb) {
  const int wid = threadIdx.x >> 6;
  const int lane = threadIdx.x & 63;
  const int t = blockIdx.x * 4 + wid;

  const float4* xrow = (const float4*)(x + (size_t)t * DM);
  ushort4* xbrow = (ushort4*)(xb + (size_t)t * DM);

  double part[NE];
#pragma unroll
  for (int e = 0; e < NE; ++e) part[e] = 0.0;

#pragma unroll
  for (int q = 0; q < 4; ++q) {
    float4 v = xrow[q * 64 + lane];
    ushort4 s;
    s.x = f2bf(v.x); s.y = f2bf(v.y); s.z = f2bf(v.z); s.w = f2bf(v.w);
    xbrow[q * 64 + lane] = s;
#pragma unroll
    for (int e = 0; e < NE; ++e) {
      float4 w = ((const float4*)(gw + (size_t)e * DM))[q * 64 + lane];
      part[e] += (double)v.x * w.x + (double)v.y * w.y +
                 (double)v.z * w.z + (double)v.w * w.w;
    }
  }
#pragma unroll
  for (int off = 32; off; off >>= 1) {
#pragma unroll
    for (int e = 0; e < NE; ++e) part[e] += __shfl_down(part[e], off);
  }
  if (lane == 0) {
    double best = part[0] + (double)gb[0];
    int bi = 0;
#pragma unroll
    for (int e = 1; e < NE; ++e) {
      double le = part[e] + (double)gb[e];
      if (le > best) { best = le; bi = e; }  // strict > => first-max wins
    }
    int pos = atomicAdd(&counts[bi], 1);
    bucket[bi * NT + pos] = t;
  }
}

// ---------------------------------------------------------------------------
// Routed GEMM: C[token,:] = act(gather(A)[token,:] @ B[e] + bias[e])
// A is bf16 [*, lda] gathered via bucket; B is fp32 [K][N] per expert,
// converted to bf16 in-register while staging to LDS (transposed [BN][BK]).
// RELU_BF16: relu + bf16 output (GEMM1->h), else fp32 output (GEMM2->out).
// ---------------------------------------------------------------------------
template <bool RELU_BF16>
__global__ __launch_bounds__(256, 2) void moe_gemm_kernel(
    const __hip_bfloat16* __restrict__ Aall, int lda,
    const float* __restrict__ Ball, int K, int N,
    const float* __restrict__ biasAll, const int* __restrict__ counts,
    const int* __restrict__ bucket, void* __restrict__ Out, int ldo) {
  const int e = blockIdx.z;
  const int cnt = counts[e];
  const int m0 = blockIdx.y * BM;
  if (m0 >= cnt) return;
  const int n0 = blockIdx.x * BN;

  const float* Bp = Ball + (size_t)e * K * N;
  const float* bias = biasAll + (size_t)e * N;
  const int* buck = bucket + e * NT;

  __shared__ __align__(16) __hip_bfloat16 As[2][BM][BKP];
  __shared__ __align__(16) __hip_bfloat16 Bs[2][BN][BKP];

  const int tid = threadIdx.x;
  const int lane = tid & 63;
  const int wid = tid >> 6;
  const int wm = (wid >> 1) * 64;
  const int wn = (wid & 1) * 64;
  const int fr = lane & 15;  // fragment row (A) / col (B)
  const int ks = lane >> 4;  // k-slot: 8 elements each

  // A staging: 2 threads per row, 16 bf16 (32 B) each
  const int ar = tid >> 1;
  const int ah = tid & 1;
  const int atok = buck[min(m0 + ar, cnt - 1)];
  const __hip_bfloat16* aptr = Aall + (size_t)atok * lda + ah * 16;

  // B staging: thread covers cols {bc,bc+32,bc+64,bc+96} x rows bk0..bk0+3
  const int bc = tid & 31;
  const int bk0 = (tid >> 5) * 4;

  f32x4 acc[4][4];
#pragma unroll
  for (int m = 0; m < 4; ++m)
#pragma unroll
    for (int n = 0; n < 4; ++n) acc[m][n] = (f32x4){0.f, 0.f, 0.f, 0.f};

  const int KT = K / BK;
  uint4 ra0, ra1;
  float rb[4][4];  // [k-sub][col-group]

  // ---- prologue: load + write tile 0
  {
    const uint4* p = (const uint4*)(aptr);
    ra0 = p[0]; ra1 = p[1];
    const float* bbase = Bp + (size_t)bk0 * N + n0 + bc;
#pragma unroll
    for (int i = 0; i < 4; ++i)
#pragma unroll
      for (int j = 0; j < 4; ++j) rb[i][j] = bbase[(size_t)i * N + 32 * j];
  }
  {
    *(uint4*)&As[0][ar][ah * 16] = ra0;
    *(uint4*)&As[0][ar][ah * 16 + 8] = ra1;
#pragma unroll
    for (int j = 0; j < 4; ++j) {
      ushort4 w;
      w.x = f2bf(rb[0][j]); w.y = f2bf(rb[1][j]);
      w.z = f2bf(rb[2][j]); w.w = f2bf(rb[3][j]);
      *(ushort4*)&Bs[0][bc + 32 * j][bk0] = w;
    }
  }
  __syncthreads();

  for (int kt = 0; kt < KT; ++kt) {
    const int buf = kt & 1;
    if (kt + 1 < KT) {  // prefetch next tile into regs (overlaps compute)
      const uint4* p = (const uint4*)(aptr + (size_t)(kt + 1) * BK);
      ra0 = p[0]; ra1 = p[1];
      const float* bbase = Bp + (size_t)((kt + 1) * BK + bk0) * N + n0 + bc;
#pragma unroll
      for (int i = 0; i < 4; ++i)
#pragma unroll
        for (int j = 0; j < 4; ++j) rb[i][j] = bbase[(size_t)i * N + 32 * j];
    }

    bf16x8 afr[4], bfr[4];
#pragma unroll
    for (int m = 0; m < 4; ++m)
      afr[m] = *(const bf16x8*)&As[buf][wm + m * 16 + fr][ks * 8];
#pragma unroll
    for (int n = 0; n < 4; ++n)
      bfr[n] = *(const bf16x8*)&Bs[buf][wn + n * 16 + fr][ks * 8];
#pragma unroll
    for (int m = 0; m < 4; ++m)
#pragma unroll
      for (int n = 0; n < 4; ++n)
        acc[m][n] = __builtin_amdgcn_mfma_f32_16x16x32_bf16(afr[m], bfr[n],
                                                            acc[m][n], 0, 0, 0);

    __syncthreads();
    if (kt + 1 < KT) {
      *(uint4*)&As[buf ^ 1][ar][ah * 16] = ra0;
      *(uint4*)&As[buf ^ 1][ar][ah * 16 + 8] = ra1;
#pragma unroll
      for (int j = 0; j < 4; ++j) {
        ushort4 w;
        w.x = f2bf(rb[0][j]); w.y = f2bf(rb[1][j]);
        w.z = f2bf(rb[2][j]); w.w = f2bf(rb[3][j]);
        *(ushort4*)&Bs[buf ^ 1][bc + 32 * j][bk0] = w;
      }
      __syncthreads();
    }
  }

  // ---- epilogue: bias (+relu) and scatter by token
  float* outF = (float*)Out;
  __hip_bfloat16* outB = (__hip_bfloat16*)Out;
#pragma unroll
  for (int m = 0; m < 4; ++m) {
#pragma unroll
    for (int r = 0; r < 4; ++r) {
      const int row = wm + m * 16 + ks * 4 + r;  // C/D: row=(lane>>4)*4+reg
      const int slot = m0 + row;
      if (slot < cnt) {
        const int tok = buck[slot];
#pragma unroll
        for (int n = 0; n < 4; ++n) {
          const int col = n0 + wn + n * 16 + fr;  // C/D: col=lane&15
          float v = acc[m][n][r] + bias[col];
          if (RELU_BF16) {
            v = v > 0.f ? v : 0.f;
            outB[(size_t)tok * ldo + col] = __float2bfloat16(v);
          } else {
            outF[(size_t)tok * ldo + col] = v;
          }
        }
      }
    }
  }
}

extern "C" void kernel_launch(void* const* d_in, const int* in_sizes, int n_in,
                              void* d_out, int out_size, void* d_ws,
                              size_t ws_size, hipStream_t stream) {
  const float* x = (const float*)d_in[0];
  const float* gw = (const float*)d_in[1];
  const float* gb = (const float*)d_in[2];
  const float* w1 = (const float*)d_in[3];
  const float* b1 = (const float*)d_in[4];
  const float* w2 = (const float*)d_in[5];
  const float* b2 = (const float*)d_in[6];

  // ws layout (needs ~40.2 MB):
  //   counts: 8 int @ 0
  //   bucket: 8*4096 int @ 256
  //   xb:     4096x1024 bf16 @ 256+128K
  //   h:      4096x4096 bf16 after xb
  char* ws = (char*)d_ws;
  int* counts = (int*)ws;
  int* bucket = (int*)(ws + 256);
  __hip_bfloat16* xb = (__hip_bfloat16*)(ws + 256 + (size_t)NE * NT * 4);
  __hip_bfloat16* h =
      (__hip_bfloat16*)(ws + 256 + (size_t)NE * NT * 4 + (size_t)NT * DM * 2);
  (void)ws_size; (void)in_sizes; (void)n_in; (void)out_size;

  hipMemsetAsync(counts, 0, NE * sizeof(int), stream);
  gate_route_kernel<<<NT / 4, 256, 0, stream>>>(x, gw, gb, counts, bucket, xb);

  dim3 g1(DH / BN, NT / BM, NE);
  moe_gemm_kernel<true><<<g1, 256, 0, stream>>>(xb, DM, w1, DM, DH, b1, counts,
                                                bucket, (void*)h, DH);
  dim3 g2(DM / BN, NT / BM, NE);
  moe_gemm_kernel<false><<<g2, 256, 0, stream>>>(h, DH, w2, DH, DM, b2, counts,
                                                 bucket, d_out, DM);
}

// Round 2
// 303.977 us; speedup vs baseline: 1.2336x; 1.2336x over previous
//
#include <hip/hip_runtime.h>
#include <hip/hip_bf16.h>

#define NT 4096   // tokens
#define DM 1024   // d_model
#define DH 4096   // d_hidden
#define NE 8      // experts

#define BM 128
#define BN 128
#define BK 32
#define KSPLIT 4
#define BKP 40    // fallback-path LDS pad

typedef short bf16x8 __attribute__((ext_vector_type(8)));
typedef float f32x4 __attribute__((ext_vector_type(4)));

// ws layout (fast path) ------------------------------------------------------
#define O_COUNTS 0ull
#define O_OFF    64ull
#define O_BUCKET 256ull
#define O_XB     (O_BUCKET + (size_t)NE * NT * 4)            // 131328
#define O_H      (O_XB + (size_t)NT * DM * 2)                // +8 MB
#define O_W1T    (O_H + (size_t)NT * DH * 2)                 // +32 MB
#define O_W2T    (O_W1T + (size_t)NE * DM * DH * 2)          // +64 MB
#define WS_NEED  (O_W2T + (size_t)NE * DH * DM * 2)          // ~168 MiB
#define O_P      O_W1T  // split-K partials (4*NT*DM*4 = 64 MB) alias dead w1t

static __device__ __forceinline__ unsigned short f2bf(float f) {
  union { __hip_bfloat16 h; unsigned short u; } cv;
  cv.h = __float2bfloat16(f);
  return cv.u;
}

static __device__ __forceinline__ void gload16(const void* g, void* l) {
  __builtin_amdgcn_global_load_lds(
      (const __attribute__((address_space(1))) void*)g,
      (__attribute__((address_space(3))) void*)l, 16, 0, 0);
}

// ---------------------------------------------------------------------------
// Gate: one wave per token. 8 logits (double accum -> first-max argmax),
// scatter token into expert bucket, convert x row to bf16.
// ---------------------------------------------------------------------------
__global__ __launch_bounds__(256) void gate_route_kernel(
    const float* __restrict__ x, const float* __restrict__ gw,
    const float* __restrict__ gb, int* __restrict__ counts,
    int* __restrict__ bucket, __hip_bfloat16* __restrict__ xb) {
  const int wid = threadIdx.x >> 6;
  const int lane = threadIdx.x & 63;
  const int t = blockIdx.x * 4 + wid;

  const float4* xrow = (const float4*)(x + (size_t)t * DM);
  ushort4* xbrow = (ushort4*)(xb + (size_t)t * DM);

  double part[NE];
#pragma unroll
  for (int e = 0; e < NE; ++e) part[e] = 0.0;

#pragma unroll
  for (int q = 0; q < 4; ++q) {
    float4 v = xrow[q * 64 + lane];
    ushort4 s;
    s.x = f2bf(v.x); s.y = f2bf(v.y); s.z = f2bf(v.z); s.w = f2bf(v.w);
    xbrow[q * 64 + lane] = s;
#pragma unroll
    for (int e = 0; e < NE; ++e) {
      float4 w = ((const float4*)(gw + (size_t)e * DM))[q * 64 + lane];
      part[e] += (double)v.x * w.x + (double)v.y * w.y +
                 (double)v.z * w.z + (double)v.w * w.w;
    }
  }
#pragma unroll
  for (int off = 32; off; off >>= 1) {
#pragma unroll
    for (int e = 0; e < NE; ++e) part[e] += __shfl_down(part[e], off);
  }
  if (lane == 0) {
    double best = part[0] + (double)gb[0];
    int bi = 0;
#pragma unroll
    for (int e = 1; e < NE; ++e) {
      double le = part[e] + (double)gb[e];
      if (le > best) { best = le; bi = e; }
    }
    int pos = atomicAdd(&counts[bi], 1);
    bucket[bi * NT + pos] = t;
  }
}

__global__ void prefix_kernel(const int* __restrict__ counts,
                              int* __restrict__ off) {
  if (threadIdx.x == 0 && blockIdx.x == 0) {
    int r = 0;
#pragma unroll
    for (int e = 0; e < NE; ++e) { off[e] = r; r += counts[e]; }
    off[NE] = r;
  }
}

// ---------------------------------------------------------------------------
// Transpose-convert: src [E][K][N] fp32 -> dst [E][N][K] bf16 (64x64 tiles).
// ---------------------------------------------------------------------------
__global__ __launch_bounds__(256) void convert_tr_kernel(
    const float* __restrict__ src, __hip_bfloat16* __restrict__ dst, int K,
    int N) {
  const int e = blockIdx.z;
  const int n0 = blockIdx.x * 64, k0 = blockIdx.y * 64;
  const float* S = src + (size_t)e * K * N;
  __hip_bfloat16* D = dst + (size_t)e * K * N;
  __shared__ __align__(16) __hip_bfloat16 Ls[64][72];  // 144 B rows (16-mult)
  const int tid = threadIdx.x;
  const int rk = tid >> 4, c4 = tid & 15;
#pragma unroll
  for (int j = 0; j < 4; ++j) {
    const int k = rk + 16 * j;
    float4 v = *(const float4*)(S + (size_t)(k0 + k) * N + n0 + c4 * 4);
    Ls[c4 * 4 + 0][k] = __float2bfloat16(v.x);
    Ls[c4 * 4 + 1][k] = __float2bfloat16(v.y);
    Ls[c4 * 4 + 2][k] = __float2bfloat16(v.z);
    Ls[c4 * 4 + 3][k] = __float2bfloat16(v.w);
  }
  __syncthreads();
  const int rn = tid >> 2, q = tid & 3;
#pragma unroll
  for (int j = 0; j < 2; ++j) {
    const int ch = q + 4 * j;
    uint4 w = *(const uint4*)&Ls[rn][ch * 8];
    *(uint4*)(D + (size_t)(n0 + rn) * K + k0 + ch * 8) = w;
  }
}

// ---------------------------------------------------------------------------
// m97-structure routed GEMM: 128x128 tile, BK=32, global_load_lds(16B)
// staging for BOTH operands, 2 barriers / K-step, 16 MFMA / wave / K-step.
// MODE 0: A = xb gathered via bucket (per-lane global addr), out = relu(+b1)
//         -> h (bf16, bucket-slot order rows goff+slot).
// MODE 1: A = h contiguous rows, K-window kq*1024..+1024, out = fp32 partial
//         P[kq][goff+slot][:].
// ---------------------------------------------------------------------------
template <int MODE>
__global__ __launch_bounds__(256) void moe_gemm_fast(
    const __hip_bfloat16* __restrict__ A, const __hip_bfloat16* __restrict__ B,
    const float* __restrict__ biasAll, const int* __restrict__ counts,
    const int* __restrict__ off, const int* __restrict__ bucket,
    void* __restrict__ Out, int Ktot, int N, int lda) {
  const int e = blockIdx.z & (NE - 1);
  const int kq = blockIdx.z >> 3;
  const int cnt = counts[e];
  const int m0 = blockIdx.y * BM;
  if (m0 >= cnt) return;
  const int goff = off[e];
  const int n0 = blockIdx.x * BN;
  const int kbase = kq * (DH / KSPLIT);  // 0 for MODE 0

  __shared__ __align__(16) __hip_bfloat16 As[BM][BK];
  __shared__ __align__(16) __hip_bfloat16 Bs[BN][BK];

  const int tid = threadIdx.x;
  const int lane = tid & 63;
  const int wid = tid >> 6;
  const int lr = lane >> 2, lc = lane & 3;  // 16 rows x 64 B per gl_lds inst

  const int s0 = min(m0 + 32 * wid + lr, cnt - 1);
  const int s1 = min(m0 + 32 * wid + 16 + lr, cnt - 1);
  const __hip_bfloat16 *aP0, *aP1;
  if (MODE == 0) {
    aP0 = A + (size_t)bucket[e * NT + s0] * lda + lc * 8;
    aP1 = A + (size_t)bucket[e * NT + s1] * lda + lc * 8;
  } else {
    aP0 = A + (size_t)(goff + s0) * lda + kbase + lc * 8;
    aP1 = A + (size_t)(goff + s1) * lda + kbase + lc * 8;
  }
  const __hip_bfloat16* bP0 =
      B + ((size_t)e * N + n0 + 32 * wid + lr) * Ktot + kbase + lc * 8;
  const __hip_bfloat16* bP1 = bP0 + (size_t)16 * Ktot;

  __hip_bfloat16* dA0 = &As[32 * wid][0];
  __hip_bfloat16* dA1 = &As[32 * wid + 16][0];
  __hip_bfloat16* dB0 = &Bs[32 * wid][0];
  __hip_bfloat16* dB1 = &Bs[32 * wid + 16][0];

  const int wm = (wid >> 1) * 64, wn = (wid & 1) * 64;
  const int fr = lane & 15, ks = lane >> 4;

  f32x4 acc[4][4];
#pragma unroll
  for (int m = 0; m < 4; ++m)
#pragma unroll
    for (int n = 0; n < 4; ++n) acc[m][n] = (f32x4){0.f, 0.f, 0.f, 0.f};

  for (int kt = 0; kt < 32; ++kt) {
    const int ko = kt * BK;
    gload16(aP0 + ko, dA0);
    gload16(aP1 + ko, dA1);
    gload16(bP0 + ko, dB0);
    gload16(bP1 + ko, dB1);
    __syncthreads();  // vmcnt(0) drain -> tile visible
    bf16x8 afr[4], bfr[4];
#pragma unroll
    for (int m = 0; m < 4; ++m)
      afr[m] = *(const bf16x8*)&As[wm + m * 16 + fr][ks * 8];
#pragma unroll
    for (int n = 0; n < 4; ++n)
      bfr[n] = *(const bf16x8*)&Bs[wn + n * 16 + fr][ks * 8];
#pragma unroll
    for (int m = 0; m < 4; ++m)
#pragma unroll
      for (int n = 0; n < 4; ++n)
        acc[m][n] = __builtin_amdgcn_mfma_f32_16x16x32_bf16(afr[m], bfr[n],
                                                            acc[m][n], 0, 0, 0);
    __syncthreads();  // all reads done before next overwrite
  }

  if (MODE == 0) {
    const float* bias = biasAll + (size_t)e * DH;
    __hip_bfloat16* Hout = (__hip_bfloat16*)Out;
#pragma unroll
    for (int m = 0; m < 4; ++m)
#pragma unroll
      for (int r = 0; r < 4; ++r) {
        const int slot = m0 + wm + m * 16 + ks * 4 + r;
        if (slot < cnt) {
          __hip_bfloat16* orow = Hout + (size_t)(goff + slot) * DH;
#pragma unroll
          for (int n = 0; n < 4; ++n) {
            const int col = n0 + wn + n * 16 + fr;
            float v = acc[m][n][r] + bias[col];
            orow[col] = __float2bfloat16(v > 0.f ? v : 0.f);
          }
        }
      }
  } else {
    float* Pout = (float*)Out + (size_t)kq * NT * DM;
#pragma unroll
    for (int m = 0; m < 4; ++m)
#pragma unroll
      for (int r = 0; r < 4; ++r) {
        const int slot = m0 + wm + m * 16 + ks * 4 + r;
        if (slot < cnt) {
          float* orow = Pout + (size_t)(goff + slot) * DM;
#pragma unroll
          for (int n = 0; n < 4; ++n) {
            const int col = n0 + wn + n * 16 + fr;
            orow[col] = acc[m][n][r];
          }
        }
      }
  }
}

// ---------------------------------------------------------------------------
// Reduce split-K partials, add b2, scatter slot -> token.
// ---------------------------------------------------------------------------
__global__ __launch_bounds__(256) void reduce_out_kernel(
    const float* __restrict__ P, const float* __restrict__ b2,
    const int* __restrict__ off, const int* __restrict__ bucket,
    float* __restrict__ out) {
  const int gs = blockIdx.x;
  int e = 0;
#pragma unroll
  for (int i = 1; i < NE; ++i) e = (gs >= off[i]) ? i : e;
  const int tok = bucket[e * NT + (gs - off[e])];
  const int c = threadIdx.x * 4;
  float4 v = *(const float4*)(P + (size_t)gs * DM + c);
#pragma unroll
  for (int q = 1; q < KSPLIT; ++q) {
    float4 p = *(const float4*)(P + ((size_t)q * NT + gs) * DM + c);
    v.x += p.x; v.y += p.y; v.z += p.z; v.w += p.w;
  }
  float4 b = *(const float4*)(b2 + (size_t)e * DM + c);
  v.x += b.x; v.y += b.y; v.z += b.z; v.w += b.w;
  *(float4*)(out + (size_t)tok * DM + c) = v;
}

// ---------------------------------------------------------------------------
// Fallback (round-1 kernel) for small ws_size.
// ---------------------------------------------------------------------------
template <bool RELU_BF16>
__global__ __launch_bounds__(256, 2) void moe_gemm_fallback(
    const __hip_bfloat16* __restrict__ Aall, int lda,
    const float* __restrict__ Ball, int K, int N,
    const float* __restrict__ biasAll, const int* __restrict__ counts,
    const int* __restrict__ bucket, void* __restrict__ Out, int ldo) {
  const int e = blockIdx.z;
  const int cnt = counts[e];
  const int m0 = blockIdx.y * BM;
  if (m0 >= cnt) return;
  const int n0 = blockIdx.x * BN;

  const float* Bp = Ball + (size_t)e * K * N;
  const float* bias = biasAll + (size_t)e * N;
  const int* buck = bucket + e * NT;

  __shared__ __align__(16) __hip_bfloat16 As[2][BM][BKP];
  __shared__ __align__(16) __hip_bfloat16 Bs[2][BN][BKP];

  const int tid = threadIdx.x;
  const int lane = tid & 63;
  const int wid = tid >> 6;
  const int wm = (wid >> 1) * 64;
  const int wn = (wid & 1) * 64;
  const int fr = lane & 15;
  const int ks = lane >> 4;

  const int ar = tid >> 1;
  const int ah = tid & 1;
  const int atok = buck[min(m0 + ar, cnt - 1)];
  const __hip_bfloat16* aptr = Aall + (size_t)atok * lda + ah * 16;

  const int bc = tid & 31;
  const int bk0 = (tid >> 5) * 4;

  f32x4 acc[4][4];
#pragma unroll
  for (int m = 0; m < 4; ++m)
#pragma unroll
    for (int n = 0; n < 4; ++n) acc[m][n] = (f32x4){0.f, 0.f, 0.f, 0.f};

  const int KT = K / BK;
  uint4 ra0, ra1;
  float rb[4][4];

  {
    const uint4* p = (const uint4*)(aptr);
    ra0 = p[0]; ra1 = p[1];
    const float* bbase = Bp + (size_t)bk0 * N + n0 + bc;
#pragma unroll
    for (int i = 0; i < 4; ++i)
#pragma unroll
      for (int j = 0; j < 4; ++j) rb[i][j] = bbase[(size_t)i * N + 32 * j];
  }
  {
    *(uint4*)&As[0][ar][ah * 16] = ra0;
    *(uint4*)&As[0][ar][ah * 16 + 8] = ra1;
#pragma unroll
    for (int j = 0; j < 4; ++j) {
      ushort4 w;
      w.x = f2bf(rb[0][j]); w.y = f2bf(rb[1][j]);
      w.z = f2bf(rb[2][j]); w.w = f2bf(rb[3][j]);
      *(ushort4*)&Bs[0][bc + 32 * j][bk0] = w;
    }
  }
  __syncthreads();

  for (int kt = 0; kt < KT; ++kt) {
    const int buf = kt & 1;
    if (kt + 1 < KT) {
      const uint4* p = (const uint4*)(aptr + (size_t)(kt + 1) * BK);
      ra0 = p[0]; ra1 = p[1];
      const float* bbase = Bp + (size_t)((kt + 1) * BK + bk0) * N + n0 + bc;
#pragma unroll
      for (int i = 0; i < 4; ++i)
#pragma unroll
        for (int j = 0; j < 4; ++j) rb[i][j] = bbase[(size_t)i * N + 32 * j];
    }

    bf16x8 afr[4], bfr[4];
#pragma unroll
    for (int m = 0; m < 4; ++m)
      afr[m] = *(const bf16x8*)&As[buf][wm + m * 16 + fr][ks * 8];
#pragma unroll
    for (int n = 0; n < 4; ++n)
      bfr[n] = *(const bf16x8*)&Bs[buf][wn + n * 16 + fr][ks * 8];
#pragma unroll
    for (int m = 0; m < 4; ++m)
#pragma unroll
      for (int n = 0; n < 4; ++n)
        acc[m][n] = __builtin_amdgcn_mfma_f32_16x16x32_bf16(afr[m], bfr[n],
                                                            acc[m][n], 0, 0, 0);

    __syncthreads();
    if (kt + 1 < KT) {
      *(uint4*)&As[buf ^ 1][ar][ah * 16] = ra0;
      *(uint4*)&As[buf ^ 1][ar][ah * 16 + 8] = ra1;
#pragma unroll
      for (int j = 0; j < 4; ++j) {
        ushort4 w;
        w.x = f2bf(rb[0][j]); w.y = f2bf(rb[1][j]);
        w.z = f2bf(rb[2][j]); w.w = f2bf(rb[3][j]);
        *(ushort4*)&Bs[buf ^ 1][bc + 32 * j][bk0] = w;
      }
      __syncthreads();
    }
  }

  float* outF = (float*)Out;
  __hip_bfloat16* outB = (__hip_bfloat16*)Out;
#pragma unroll
  for (int m = 0; m < 4; ++m) {
#pragma unroll
    for (int r = 0; r < 4; ++r) {
      const int row = wm + m * 16 + ks * 4 + r;
      const int slot = m0 + row;
      if (slot < cnt) {
        const int tok = buck[slot];
#pragma unroll
        for (int n = 0; n < 4; ++n) {
          const int col = n0 + wn + n * 16 + fr;
          float v = acc[m][n][r] + bias[col];
          if (RELU_BF16) {
            v = v > 0.f ? v : 0.f;
            outB[(size_t)tok * ldo + col] = __float2bfloat16(v);
          } else {
            outF[(size_t)tok * ldo + col] = v;
          }
        }
      }
    }
  }
}

extern "C" void kernel_launch(void* const* d_in, const int* in_sizes, int n_in,
                              void* d_out, int out_size, void* d_ws,
                              size_t ws_size, hipStream_t stream) {
  const float* x = (const float*)d_in[0];
  const float* gw = (const float*)d_in[1];
  const float* gb = (const float*)d_in[2];
  const float* w1 = (const float*)d_in[3];
  const float* b1 = (const float*)d_in[4];
  const float* w2 = (const float*)d_in[5];
  const float* b2 = (const float*)d_in[6];
  (void)in_sizes; (void)n_in; (void)out_size;

  char* ws = (char*)d_ws;
  int* counts = (int*)(ws + O_COUNTS);
  int* off = (int*)(ws + O_OFF);
  int* bucket = (int*)(ws + O_BUCKET);
  __hip_bfloat16* xb = (__hip_bfloat16*)(ws + O_XB);
  __hip_bfloat16* h = (__hip_bfloat16*)(ws + O_H);

  hipMemsetAsync(ws, 0, 256, stream);
  gate_route_kernel<<<NT / 4, 256, 0, stream>>>(x, gw, gb, counts, bucket, xb);

  if (ws_size >= WS_NEED) {
    __hip_bfloat16* w1t = (__hip_bfloat16*)(ws + O_W1T);
    __hip_bfloat16* w2t = (__hip_bfloat16*)(ws + O_W2T);
    float* P = (float*)(ws + O_P);

    prefix_kernel<<<1, 64, 0, stream>>>(counts, off);
    convert_tr_kernel<<<dim3(DH / 64, DM / 64, NE), 256, 0, stream>>>(
        w1, w1t, DM, DH);
    moe_gemm_fast<0><<<dim3(DH / BN, NT / BM, NE), 256, 0, stream>>>(
        xb, w1t, b1, counts, off, bucket, (void*)h, DM, DH, DM);
    convert_tr_kernel<<<dim3(DM / 64, DH / 64, NE), 256, 0, stream>>>(
        w2, w2t, DH, DM);
    moe_gemm_fast<1><<<dim3(DM / BN, NT / BM, NE * KSPLIT), 256, 0, stream>>>(
        h, w2t, nullptr, counts, off, bucket, (void*)P, DH, DM, DH);
    reduce_out_kernel<<<NT, 256, 0, stream>>>(P, b2, off, bucket,
                                              (float*)d_out);
  } else {
    // small-ws fallback: round-1 path (h in token order, fused fp32-B GEMMs)
    dim3 g1(DH / BN, NT / BM, NE);
    moe_gemm_fallback<true><<<g1, 256, 0, stream>>>(
        xb, DM, w1, DM, DH, b1, counts, bucket, (void*)h, DH);
    dim3 g2(DM / BN, NT / BM, NE);
    moe_gemm_fallback<false><<<g2, 256, 0, stream>>>(
        h, DH, w2, DH, DM, b2, counts, bucket, d_out, DM);
  }
}